// Round 7
// baseline (207.063 us; speedup 1.0000x reference)
//
#include <hip/hip_runtime.h>
#include <stdint.h>

typedef __attribute__((ext_vector_type(8))) short bf16x8;
typedef __attribute__((ext_vector_type(4))) short bf16x4;
typedef __attribute__((ext_vector_type(4))) float f32x4;

#define WAVES 4
#define R_STRIDE 72                    // shorts; 144 B rows (16B aligned)
#define A_STRIDE 40                    // shorts; 80 B rows (16B aligned)
#define R_LDS_SHORTS (32 * R_STRIDE)   // 2304
#define A_LDS_SHORTS (32 * A_STRIDE)   // 1280
#define WAVE_LDS (R_LDS_SHORTS + A_LDS_SHORTS)  // 3584 shorts = 7168 B per wave
#define W_LDS_OFF (WAVES * WAVE_LDS)   // 14336 shorts; W bf16 tile lives here
#define SMEM_SHORTS (W_LDS_OFF + 2048) // 16384 shorts = 32768 B -> exactly 5 blocks/CU
#define VB_STRIDE 68                   // padded fp32 row stride for reduction buffers
#define NITER 2                        // 2 iters x 4 waves x 32 rows = 256 rows (1/8 of N)
#define WS_STRIDE 2080                 // floats per partial: 2048 v + 32 suma

// Hardware packed f32->bf16 (RNE): v_cvt_pk_bf16_f32 puts bf16(%1) in the
// low half, bf16(%2) in the high half (guide T12 recipe, "lo,hi"). 1 instr
// per 2 elements vs the 5-op/element manual RNE bit-twiddle: saves ~200
// VALU ops per wave-iteration. ONLY change vs the round-4 passing kernel,
// so a pass/fail cleanly attributes round-5's failure to the tr-read.
static __device__ __forceinline__ bf16x8 cvt8(float4 a, float4 b) {
    union { int i[4]; bf16x8 v; } u;
    asm("v_cvt_pk_bf16_f32 %0, %1, %2" : "=v"(u.i[0]) : "v"(a.x), "v"(a.y));
    asm("v_cvt_pk_bf16_f32 %0, %1, %2" : "=v"(u.i[1]) : "v"(a.z), "v"(a.w));
    asm("v_cvt_pk_bf16_f32 %0, %1, %2" : "=v"(u.i[2]) : "v"(b.x), "v"(b.y));
    asm("v_cvt_pk_bf16_f32 %0, %1, %2" : "=v"(u.i[3]) : "v"(b.z), "v"(b.w));
    return u.v;
}

// Sum across the 16 lanes of a DPP row (all lanes end with the total).
static __device__ __forceinline__ float row_sum16(float x) {
    union fi { float f; int i; };
    fi a, b; a.f = x;
    b.i = __builtin_amdgcn_mov_dpp(a.i, 0x128, 0xf, 0xf, false); a.f += b.f;
    b.i = __builtin_amdgcn_mov_dpp(a.i, 0x124, 0xf, 0xf, false); a.f += b.f;
    b.i = __builtin_amdgcn_mov_dpp(a.i, 0x122, 0xf, 0xf, false); a.f += b.f;
    b.i = __builtin_amdgcn_mov_dpp(a.i, 0x121, 0xf, 0xf, false); a.f += b.f;
    return a.f;
}

// DESIGN FOR 64 VGPRs (rounds 1-3): the allocator squeezes these kernels to
// 64 VGPRs regardless of launch-bounds hints. Live set kept ~60-70 by
// (a) W fragments in a shared 4 KB LDS tile (XOR-swizzled, bank-balanced),
// (b) per-s processing halving af/d1 transients, (c) cvt_pk conversion.
// LDS = exactly 32 KiB/block -> 5 blocks/CU resident.
__global__ __launch_bounds__(256, 2)
void netvlad_partial(const float* __restrict__ R,
                     const float* __restrict__ W,
                     const float* __restrict__ bias,
                     float* __restrict__ ws)
{
    __shared__ short smem[SMEM_SHORTS];   // 32768 B

    const int tid  = threadIdx.x;
    const int wave = tid >> 6;
    const int lane = tid & 63;
    const int l15  = lane & 15;
    const int quad = lane >> 4;
    const int bid  = blockIdx.x;
    const int m    = bid >> 3;
    const int h    = bid & 7;

    short* r_lds = smem + wave * WAVE_LDS;
    short* a_lds = r_lds + R_LDS_SHORTS;
    short* w_lds = smem + W_LDS_OFF;

    const float* Rm = R + ((size_t)m * 2048 + (size_t)h * 256) * 64;

    // Stage W (32x64) as bf16 into shared LDS. Every wave writes identical
    // data -> benign race, no barrier needed. Swizzle: k*64 + (c^((k&7)<<3));
    // fragment reads are contiguous 16 B, 8 accesses/bank = the floor.
#pragma unroll
    for (int kt = 0; kt < 2; ++kt)
#pragma unroll
        for (int cc = 0; cc < 2; ++cc) {
            const int k = kt*16 + l15;
            const int c = cc*32 + quad*8;
            const float* wp = W + k*64 + c;
            bf16x8 wv = cvt8(*(const float4*)wp, *(const float4*)(wp + 4));
            *(bf16x8*)(w_lds + k*64 + (c ^ ((k & 7) << 3))) = wv;
        }

    float bval[2];
    bval[0] = bias[l15];
    bval[1] = bias[16 + l15];

    f32x4 acc[2][4];   // v accumulator tiles [ktile][ctile], D-layout
#pragma unroll
    for (int kt = 0; kt < 2; ++kt)
#pragma unroll
        for (int ct = 0; ct < 4; ++ct)
            acc[kt][ct] = (f32x4){0.f, 0.f, 0.f, 0.f};
    float suma[2] = {0.f, 0.f};

#pragma unroll 1
    for (int it = 0; it < NITER; ++it) {
        const int n0 = it * (WAVES * 32) + wave * 32;

        // per-s: load+cvt+stage -> GEMM1 -> softmax (halves transient regs)
#pragma unroll
        for (int s = 0; s < 2; ++s) {
            const int g = (s*2 + (l15 >> 3)) & 3;          // (n>>3)&3 for n=s*16+l15
            bf16x8 af0, af1;
            {
                const float* rp = Rm + (size_t)(n0 + s*16 + l15)*64 + quad*8;
                af0 = cvt8(*(const float4*)rp, *(const float4*)(rp + 4));
                *(bf16x8*)(r_lds + (s*16 + l15)*R_STRIDE + ((quad*8) ^ (g << 4))) = af0;
            }
            {
                const float* rp = Rm + (size_t)(n0 + s*16 + l15)*64 + 32 + quad*8;
                af1 = cvt8(*(const float4*)rp, *(const float4*)(rp + 4));
                *(bf16x8*)(r_lds + (s*16 + l15)*R_STRIDE + ((32 + quad*8) ^ (g << 4))) = af1;
            }

            // GEMM1 for this s: W fragments re-read from LDS per kt (transient)
            f32x4 d1s[2];
#pragma unroll
            for (int kt = 0; kt < 2; ++kt) {
                const int k = kt*16 + l15;
                const bf16x8 w0 = *(const bf16x8*)(w_lds + k*64 + ((quad*8)      ^ ((k & 7) << 3)));
                const bf16x8 w1 = *(const bf16x8*)(w_lds + k*64 + ((32 + quad*8) ^ ((k & 7) << 3)));
                f32x4 d = (f32x4){0.f, 0.f, 0.f, 0.f};
                d = __builtin_amdgcn_mfma_f32_16x16x32_bf16(af0, w0, d, 0, 0, 0);
                d = __builtin_amdgcn_mfma_f32_16x16x32_bf16(af1, w1, d, 0, 0, 0);
                d1s[kt] = d;
            }

            // softmax over k (row = s*16 + quad*4 + r, k = kt*16 + l15)
            float a0v[4], a1v[4];
            float a0s = 0.f, a1s = 0.f;
#pragma unroll
            for (int r = 0; r < 4; ++r) {
                float l0 = d1s[0][r] + bval[0];
                float l1 = d1s[1][r] + bval[1];
                float e0 = __expf(l0);
                float e1 = __expf(l1);
                float ss = row_sum16(e0 + e1);             // VALU DPP, off the LDS pipe
                float rs = __builtin_amdgcn_rcpf(ss);
                a0v[r] = e0 * rs; a1v[r] = e1 * rs;
                a0s += a0v[r]; a1s += a1v[r];
            }
            suma[0] += a0s; suma[1] += a1s;
            // pack 4 probs with 2 cvt_pk each; a_lds[k][n] (n contiguous)
            union { int i[2]; bf16x4 v; } p0, p1;
            asm("v_cvt_pk_bf16_f32 %0, %1, %2" : "=v"(p0.i[0]) : "v"(a0v[0]), "v"(a0v[1]));
            asm("v_cvt_pk_bf16_f32 %0, %1, %2" : "=v"(p0.i[1]) : "v"(a0v[2]), "v"(a0v[3]));
            asm("v_cvt_pk_bf16_f32 %0, %1, %2" : "=v"(p1.i[0]) : "v"(a1v[0]), "v"(a1v[1]));
            asm("v_cvt_pk_bf16_f32 %0, %1, %2" : "=v"(p1.i[1]) : "v"(a1v[2]), "v"(a1v[3]));
            *(bf16x4*)(a_lds + l15*A_STRIDE        + s*16 + quad*4) = p0.v;
            *(bf16x4*)(a_lds + (16 + l15)*A_STRIDE + s*16 + quad*4) = p1.v;
        }

        // A2 fragments: A[m=k][kdim=n] -> contiguous 16 B from a_lds
        bf16x8 a2[2];
#pragma unroll
        for (int kt = 0; kt < 2; ++kt)
            a2[kt] = *(bf16x8*)(a_lds + (kt*16 + l15)*A_STRIDE + quad*8);

        // GEMM2: v += a^T r ; B[kdim=n][col=c] gathered from swizzled r_lds.
        // element (n=quad*8+j, c=ct*16+l15) lives at n*R_STRIDE + (ct^quad)*16 + l15
#pragma unroll
        for (int ct = 0; ct < 4; ++ct) {
            const short* bp = r_lds + (quad*8)*R_STRIDE + ((ct ^ quad) << 4) + l15;
            bf16x8 b2;
#pragma unroll
            for (int j = 0; j < 8; ++j)
                b2[j] = bp[j*R_STRIDE];
#pragma unroll
            for (int kt = 0; kt < 2; ++kt)
                acc[kt][ct] = __builtin_amdgcn_mfma_f32_16x16x32_bf16(a2[kt], b2, acc[kt][ct], 0, 0, 0);
        }
    }

    // suma held per-lane for k = l15 (+16): fold the 4 quads together
#pragma unroll
    for (int kt = 0; kt < 2; ++kt) {
        suma[kt] += __shfl_xor(suma[kt], 16);
        suma[kt] += __shfl_xor(suma[kt], 32);
    }

    // cross-wave log-tree reduction. vbuf aliases the (dead) r/a staging LDS;
    // suma_buf aliases the (dead) W region. Both are safe after syncthreads.
    float* vbuf = (float*)smem;
    float* suma_buf = (float*)(smem + W_LDS_OFF);   // [2][32] floats, 256 B
    __syncthreads();
#pragma unroll
    for (int step = 2; step >= 1; step >>= 1) {
        if (wave >= step && wave < 2*step) {
            float* dst = vbuf + (wave - step) * (32 * VB_STRIDE);
#pragma unroll
            for (int kt = 0; kt < 2; ++kt)
#pragma unroll
                for (int ct = 0; ct < 4; ++ct)
#pragma unroll
                    for (int r = 0; r < 4; ++r)
                        dst[(kt*16 + quad*4 + r)*VB_STRIDE + ct*16 + l15] = acc[kt][ct][r];
            if (lane < 16) {
                suma_buf[(wave - step)*32 + lane]      = suma[0];
                suma_buf[(wave - step)*32 + lane + 16] = suma[1];
            }
        }
        __syncthreads();
        if (wave < step) {
            const float* src = vbuf + wave * (32 * VB_STRIDE);
#pragma unroll
            for (int kt = 0; kt < 2; ++kt)
#pragma unroll
                for (int ct = 0; ct < 4; ++ct)
#pragma unroll
                    for (int r = 0; r < 4; ++r)
                        acc[kt][ct][r] += src[(kt*16 + quad*4 + r)*VB_STRIDE + ct*16 + l15];
            suma[0] += suma_buf[wave*32 + l15];
            suma[1] += suma_buf[wave*32 + l15 + 16];
        }
        __syncthreads();
    }

    // wave 0: write block partial {v (32x64), suma (32)} to workspace
    if (wave == 0) {
        float* wp = ws + (size_t)bid * WS_STRIDE;
#pragma unroll
        for (int kt = 0; kt < 2; ++kt)
#pragma unroll
            for (int r = 0; r < 4; ++r) {
                const int k = kt*16 + quad*4 + r;
#pragma unroll
                for (int ct = 0; ct < 4; ++ct)
                    wp[k*64 + ct*16 + l15] = acc[kt][ct][r];
            }
        if (lane < 16) {
            wp[2048 + lane]      = suma[0];   // lane holds total for k = lane
            wp[2048 + 16 + lane] = suma[1];   // and k = 16 + lane
        }
    }
}

// Kernel 2: combine the eight N-slices and apply  v - suma[k]*cent[k][c].
// 256 blocks x 512 threads, one float4 of output per thread (~19 MB traffic).
__global__ __launch_bounds__(512)
void netvlad_combine(const float* __restrict__ ws,
                     const float* __restrict__ cent,
                     float* __restrict__ out)
{
    const int m   = blockIdx.x;
    const int tid = threadIdx.x;
    const float* pb = ws + (size_t)(8*m) * WS_STRIDE;

    const int k  = tid >> 4;          // 0..31
    const int c0 = (tid & 15) << 2;   // 0,4,...,60
    const int off = k*64 + c0;

    float s = 0.f;
    float4 v = {0.f, 0.f, 0.f, 0.f};
#pragma unroll
    for (int i = 0; i < 8; ++i) {
        const float* p = pb + (size_t)i * WS_STRIDE;
        s += p[2048 + k];
        const float4 vi = *(const float4*)(p + off);
        v.x += vi.x; v.y += vi.y; v.z += vi.z; v.w += vi.w;
    }

    const float4 cv = *(const float4*)(cent + off);
    float4 o;
    o.x = v.x - s * cv.x;
    o.y = v.y - s * cv.y;
    o.z = v.z - s * cv.z;
    o.w = v.w - s * cv.w;
    *(float4*)(out + (size_t)m * 2048 + off) = o;
}

extern "C" void kernel_launch(void* const* d_in, const int* in_sizes, int n_in,
                              void* d_out, int out_size, void* d_ws, size_t ws_size,
                              hipStream_t stream) {
    (void)in_sizes; (void)n_in; (void)out_size; (void)ws_size;
    const float* R = (const float*)d_in[0];   // R_seq (8,32,2048,64) fp32
    const float* W = (const float*)d_in[1];   // W (32,64) fp32
    const float* b = (const float*)d_in[2];   // b (32,) fp32
    const float* c = (const float*)d_in[3];   // centroids (32,64) fp32
    float* out = (float*)d_out;               // (8,32,32,64) fp32
    float* ws  = (float*)d_ws;                // 2048 * 2080 floats = 17 MB partials

    hipLaunchKernelGGL(netvlad_partial, dim3(2048), dim3(256), 0, stream, R, W, b, ws);
    hipLaunchKernelGGL(netvlad_combine, dim3(256), dim3(512), 0, stream, ws, c, out);
}

// Round 8
// 206.177 us; speedup vs baseline: 1.0043x; 1.0043x over previous
//
#include <hip/hip_runtime.h>
#include <stdint.h>

typedef __attribute__((ext_vector_type(8))) short bf16x8;
typedef __attribute__((ext_vector_type(4))) short bf16x4;
typedef __attribute__((ext_vector_type(4))) float f32x4;

#define WAVES 4
// r_t: TRANSPOSED r tile [c=64 rows][n=32 cols] bf16, stride 36 shorts (72 B).
// Written by 16 ds_write_b16 scatters per s (fire-and-forget, no merge chains;
// ~4-way bank conflict, hidden under GEMM1+softmax). Read by GEMM2-B as TWO
// contiguous ds_read_b64 per ct: row c=ct*16+l15, cols n=quad*8..+7.
// ST=36: row-start bank = l15*18 mod 32 -> 16 distinct banks, 2 lanes/bank =
// conflict-free reads. Replaces round-4/7's 32 chained ds_read_u16_d16
// half-register-merge gather (~120 cyc each, m117) -- the dominant latency
// chain (cvt_pk's null result in round 7 proved the chain is stall-bound,
// not VALU-bound).
#define RT_STRIDE 36
#define RT_LDS_SHORTS (64 * RT_STRIDE) // 2304
#define A_STRIDE 40                    // shorts; 80 B rows (16B aligned)
#define A_LDS_SHORTS (32 * A_STRIDE)   // 1280
#define WAVE_LDS (RT_LDS_SHORTS + A_LDS_SHORTS)  // 3584 shorts = 7168 B per wave
#define W_LDS_OFF (WAVES * WAVE_LDS)   // 14336 shorts; W bf16 tile lives here
#define SMEM_SHORTS (W_LDS_OFF + 2048) // 16384 shorts = 32768 B -> exactly 5 blocks/CU
#define VB_STRIDE 68                   // padded fp32 row stride for reduction buffers
#define NITER 2                        // 2 iters x 4 waves x 32 rows = 256 rows (1/8 of N)
#define WS_STRIDE 2080                 // floats per partial: 2048 v + 32 suma

// Hardware packed f32->bf16 (RNE): verified correct in round 7 (absmax 0.25).
static __device__ __forceinline__ bf16x8 cvt8(float4 a, float4 b) {
    union { int i[4]; bf16x8 v; } u;
    asm("v_cvt_pk_bf16_f32 %0, %1, %2" : "=v"(u.i[0]) : "v"(a.x), "v"(a.y));
    asm("v_cvt_pk_bf16_f32 %0, %1, %2" : "=v"(u.i[1]) : "v"(a.z), "v"(a.w));
    asm("v_cvt_pk_bf16_f32 %0, %1, %2" : "=v"(u.i[2]) : "v"(b.x), "v"(b.y));
    asm("v_cvt_pk_bf16_f32 %0, %1, %2" : "=v"(u.i[3]) : "v"(b.z), "v"(b.w));
    return u.v;
}

// Sum across the 16 lanes of a DPP row (all lanes end with the total).
static __device__ __forceinline__ float row_sum16(float x) {
    union fi { float f; int i; };
    fi a, b; a.f = x;
    b.i = __builtin_amdgcn_mov_dpp(a.i, 0x128, 0xf, 0xf, false); a.f += b.f;
    b.i = __builtin_amdgcn_mov_dpp(a.i, 0x124, 0xf, 0xf, false); a.f += b.f;
    b.i = __builtin_amdgcn_mov_dpp(a.i, 0x122, 0xf, 0xf, false); a.f += b.f;
    b.i = __builtin_amdgcn_mov_dpp(a.i, 0x121, 0xf, 0xf, false); a.f += b.f;
    return a.f;
}

// DESIGN FOR 64 VGPRs (rounds 1-3): the allocator squeezes these kernels to
// 64 VGPRs regardless of launch-bounds hints. Live set kept ~60-70 by
// W-in-LDS, per-s processing, cvt_pk. LDS = 32 KiB/block -> 5 blocks/CU.
__global__ __launch_bounds__(256, 2)
void netvlad_partial(const float* __restrict__ R,
                     const float* __restrict__ W,
                     const float* __restrict__ bias,
                     float* __restrict__ ws)
{
    __shared__ short smem[SMEM_SHORTS];   // 32768 B

    const int tid  = threadIdx.x;
    const int wave = tid >> 6;
    const int lane = tid & 63;
    const int l15  = lane & 15;
    const int quad = lane >> 4;
    const int bid  = blockIdx.x;
    const int m    = bid >> 3;
    const int h    = bid & 7;

    short* rt_lds = smem + wave * WAVE_LDS;
    short* a_lds  = rt_lds + RT_LDS_SHORTS;
    short* w_lds  = smem + W_LDS_OFF;

    const float* Rm = R + ((size_t)m * 2048 + (size_t)h * 256) * 64;

    // Stage W (32x64) as bf16 into shared LDS. Every wave writes identical
    // data -> benign race, no barrier needed. Swizzle: k*64 + (c^((k&7)<<3));
    // fragment reads are contiguous 16 B, 8 accesses/bank = the floor.
#pragma unroll
    for (int kt = 0; kt < 2; ++kt)
#pragma unroll
        for (int cc = 0; cc < 2; ++cc) {
            const int k = kt*16 + l15;
            const int c = cc*32 + quad*8;
            const float* wp = W + k*64 + c;
            bf16x8 wv = cvt8(*(const float4*)wp, *(const float4*)(wp + 4));
            *(bf16x8*)(w_lds + k*64 + (c ^ ((k & 7) << 3))) = wv;
        }

    float bval[2];
    bval[0] = bias[l15];
    bval[1] = bias[16 + l15];

    f32x4 acc[2][4];   // v accumulator tiles [ktile][ctile], D-layout
#pragma unroll
    for (int kt = 0; kt < 2; ++kt)
#pragma unroll
        for (int ct = 0; ct < 4; ++ct)
            acc[kt][ct] = (f32x4){0.f, 0.f, 0.f, 0.f};
    float suma[2] = {0.f, 0.f};

#pragma unroll 1
    for (int it = 0; it < NITER; ++it) {
        const int n0 = it * (WAVES * 32) + wave * 32;

        // per-s: load+cvt -> scatter to r_t -> GEMM1 -> softmax
#pragma unroll
        for (int s = 0; s < 2; ++s) {
            const int n = s*16 + l15;                     // row within 32-row tile
            bf16x8 af0, af1;
            {
                const float* rp = Rm + (size_t)(n0 + n)*64 + quad*8;
                af0 = cvt8(*(const float4*)rp, *(const float4*)(rp + 4));
            }
            {
                const float* rp = Rm + (size_t)(n0 + n)*64 + 32 + quad*8;
                af1 = cvt8(*(const float4*)rp, *(const float4*)(rp + 4));
            }

            // scatter to transposed r_t: element e -> row c = (cc*32+quad*8+e),
            // col n. 16 ds_write_b16, no waits needed here (reads are after
            // GEMM1+softmax; lgkmcnt ordering handles the dependency).
#pragma unroll
            for (int e = 0; e < 8; ++e) {
                rt_lds[(quad*8 + e)*RT_STRIDE + n]      = af0[e];
                rt_lds[(32 + quad*8 + e)*RT_STRIDE + n] = af1[e];
            }

            // GEMM1 for this s: W fragments re-read from LDS per kt (transient)
            f32x4 d1s[2];
#pragma unroll
            for (int kt = 0; kt < 2; ++kt) {
                const int k = kt*16 + l15;
                const bf16x8 w0 = *(const bf16x8*)(w_lds + k*64 + ((quad*8)      ^ ((k & 7) << 3)));
                const bf16x8 w1 = *(const bf16x8*)(w_lds + k*64 + ((32 + quad*8) ^ ((k & 7) << 3)));
                f32x4 d = (f32x4){0.f, 0.f, 0.f, 0.f};
                d = __builtin_amdgcn_mfma_f32_16x16x32_bf16(af0, w0, d, 0, 0, 0);
                d = __builtin_amdgcn_mfma_f32_16x16x32_bf16(af1, w1, d, 0, 0, 0);
                d1s[kt] = d;
            }

            // softmax over k (row = s*16 + quad*4 + r, k = kt*16 + l15)
            float a0v[4], a1v[4];
            float a0s = 0.f, a1s = 0.f;
#pragma unroll
            for (int r = 0; r < 4; ++r) {
                float l0 = d1s[0][r] + bval[0];
                float l1 = d1s[1][r] + bval[1];
                float e0 = __expf(l0);
                float e1 = __expf(l1);
                float ss = row_sum16(e0 + e1);             // VALU DPP, off the LDS pipe
                float rs = __builtin_amdgcn_rcpf(ss);
                a0v[r] = e0 * rs; a1v[r] = e1 * rs;
                a0s += a0v[r]; a1s += a1v[r];
            }
            suma[0] += a0s; suma[1] += a1s;
            // pack 4 probs with 2 cvt_pk each; a_lds[k][n] (n contiguous)
            union { int i[2]; bf16x4 v; } p0, p1;
            asm("v_cvt_pk_bf16_f32 %0, %1, %2" : "=v"(p0.i[0]) : "v"(a0v[0]), "v"(a0v[1]));
            asm("v_cvt_pk_bf16_f32 %0, %1, %2" : "=v"(p0.i[1]) : "v"(a0v[2]), "v"(a0v[3]));
            asm("v_cvt_pk_bf16_f32 %0, %1, %2" : "=v"(p1.i[0]) : "v"(a1v[0]), "v"(a1v[1]));
            asm("v_cvt_pk_bf16_f32 %0, %1, %2" : "=v"(p1.i[1]) : "v"(a1v[2]), "v"(a1v[3]));
            *(bf16x4*)(a_lds + l15*A_STRIDE        + s*16 + quad*4) = p0.v;
            *(bf16x4*)(a_lds + (16 + l15)*A_STRIDE + s*16 + quad*4) = p1.v;
        }

        // A2 fragments: A[m=k][kdim=n] -> contiguous 16 B from a_lds
        bf16x8 a2[2];
#pragma unroll
        for (int kt = 0; kt < 2; ++kt)
            a2[kt] = *(bf16x8*)(a_lds + (kt*16 + l15)*A_STRIDE + quad*8);

        // GEMM2: v += a^T r. B-frag element j = r[n=quad*8+j][c=ct*16+l15]
        // = r_t[c][quad*8+j]: two contiguous ds_read_b64 per ct (8B-aligned:
        // row byte offset = c*72, + quad*16). Conflict-free (see RT comment).
#pragma unroll
        for (int ct = 0; ct < 4; ++ct) {
            const short* bp = rt_lds + (ct*16 + l15)*RT_STRIDE + quad*8;
            union { bf16x4 h[2]; bf16x8 v; } b2;
            b2.h[0] = *(const bf16x4*)bp;
            b2.h[1] = *(const bf16x4*)(bp + 4);
#pragma unroll
            for (int kt = 0; kt < 2; ++kt)
                acc[kt][ct] = __builtin_amdgcn_mfma_f32_16x16x32_bf16(a2[kt], b2.v, acc[kt][ct], 0, 0, 0);
        }
    }

    // suma held per-lane for k = l15 (+16): fold the 4 quads together
#pragma unroll
    for (int kt = 0; kt < 2; ++kt) {
        suma[kt] += __shfl_xor(suma[kt], 16);
        suma[kt] += __shfl_xor(suma[kt], 32);
    }

    // cross-wave log-tree reduction. vbuf aliases the (dead) r/a staging LDS;
    // suma_buf aliases the (dead) W region. Both are safe after syncthreads.
    float* vbuf = (float*)smem;
    float* suma_buf = (float*)(smem + W_LDS_OFF);   // [2][32] floats, 256 B
    __syncthreads();
#pragma unroll
    for (int step = 2; step >= 1; step >>= 1) {
        if (wave >= step && wave < 2*step) {
            float* dst = vbuf + (wave - step) * (32 * VB_STRIDE);
#pragma unroll
            for (int kt = 0; kt < 2; ++kt)
#pragma unroll
                for (int ct = 0; ct < 4; ++ct)
#pragma unroll
                    for (int r = 0; r < 4; ++r)
                        dst[(kt*16 + quad*4 + r)*VB_STRIDE + ct*16 + l15] = acc[kt][ct][r];
            if (lane < 16) {
                suma_buf[(wave - step)*32 + lane]      = suma[0];
                suma_buf[(wave - step)*32 + lane + 16] = suma[1];
            }
        }
        __syncthreads();
        if (wave < step) {
            const float* src = vbuf + wave * (32 * VB_STRIDE);
#pragma unroll
            for (int kt = 0; kt < 2; ++kt)
#pragma unroll
                for (int ct = 0; ct < 4; ++ct)
#pragma unroll
                    for (int r = 0; r < 4; ++r)
                        acc[kt][ct][r] += src[(kt*16 + quad*4 + r)*VB_STRIDE + ct*16 + l15];
            suma[0] += suma_buf[wave*32 + l15];
            suma[1] += suma_buf[wave*32 + l15 + 16];
        }
        __syncthreads();
    }

    // wave 0: write block partial {v (32x64), suma (32)} to workspace
    if (wave == 0) {
        float* wp = ws + (size_t)bid * WS_STRIDE;
#pragma unroll
        for (int kt = 0; kt < 2; ++kt)
#pragma unroll
            for (int r = 0; r < 4; ++r) {
                const int k = kt*16 + quad*4 + r;
#pragma unroll
                for (int ct = 0; ct < 4; ++ct)
                    wp[k*64 + ct*16 + l15] = acc[kt][ct][r];
            }
        if (lane < 16) {
            wp[2048 + lane]      = suma[0];   // lane holds total for k = lane
            wp[2048 + 16 + lane] = suma[1];   // and k = 16 + lane
        }
    }
}

// Kernel 2: combine the eight N-slices and apply  v - suma[k]*cent[k][c].
// 256 blocks x 512 threads, one float4 of output per thread (~19 MB traffic).
__global__ __launch_bounds__(512)
void netvlad_combine(const float* __restrict__ ws,
                     const float* __restrict__ cent,
                     float* __restrict__ out)
{
    const int m   = blockIdx.x;
    const int tid = threadIdx.x;
    const float* pb = ws + (size_t)(8*m) * WS_STRIDE;

    const int k  = tid >> 4;          // 0..31
    const int c0 = (tid & 15) << 2;   // 0,4,...,60
    const int off = k*64 + c0;

    float s = 0.f;
    float4 v = {0.f, 0.f, 0.f, 0.f};
#pragma unroll
    for (int i = 0; i < 8; ++i) {
        const float* p = pb + (size_t)i * WS_STRIDE;
        s += p[2048 + k];
        const float4 vi = *(const float4*)(p + off);
        v.x += vi.x; v.y += vi.y; v.z += vi.z; v.w += vi.w;
    }

    const float4 cv = *(const float4*)(cent + off);
    float4 o;
    o.x = v.x - s * cv.x;
    o.y = v.y - s * cv.y;
    o.z = v.z - s * cv.z;
    o.w = v.w - s * cv.w;
    *(float4*)(out + (size_t)m * 2048 + off) = o;
}

extern "C" void kernel_launch(void* const* d_in, const int* in_sizes, int n_in,
                              void* d_out, int out_size, void* d_ws, size_t ws_size,
                              hipStream_t stream) {
    (void)in_sizes; (void)n_in; (void)out_size; (void)ws_size;
    const float* R = (const float*)d_in[0];   // R_seq (8,32,2048,64) fp32
    const float* W = (const float*)d_in[1];   // W (32,64) fp32
    const float* b = (const float*)d_in[2];   // b (32,) fp32
    const float* c = (const float*)d_in[3];   // centroids (32,64) fp32
    float* out = (float*)d_out;               // (8,32,32,64) fp32
    float* ws  = (float*)d_ws;                // 2048 * 2080 floats = 17 MB partials

    hipLaunchKernelGGL(netvlad_partial, dim3(2048), dim3(256), 0, stream, R, W, b, ws);
    hipLaunchKernelGGL(netvlad_combine, dim3(256), dim3(512), 0, stream, ws, c, out);
}

// Round 9
// 202.925 us; speedup vs baseline: 1.0204x; 1.0160x over previous
//
#include <hip/hip_runtime.h>
#include <stdint.h>

typedef __attribute__((ext_vector_type(8))) short bf16x8;
typedef __attribute__((ext_vector_type(4))) short bf16x4;
typedef __attribute__((ext_vector_type(4))) float f32x4;

#define WAVES 4
// Per-wave LDS (shorts):
//  nc: [16 n][64 c] bf16, XOR-swizzled col ^ ((n&7)<<3). Per-s staging tile
//      for the GEMM1 A-fragment redistribution (coalesced loads no longer
//      leave each lane holding its own fragment). b64 writes / b128 reads,
//      same verified swizzle idiom as w_lds.
//  cn: [64 c][32 n] bf16 stride 36 (round-8 verified): GEMM2-B via 2x b64.
//  a:  [32 k][40] softmax weights (round-4+ verified).
#define NC_SHORTS (16 * 64)            // 1024
#define CN_STRIDE 36
#define CN_SHORTS (64 * CN_STRIDE)     // 2304
#define A_STRIDE 40
#define A_SHORTS (32 * A_STRIDE)       // 1280
#define WAVE_LDS (NC_SHORTS + CN_SHORTS + A_SHORTS)   // 4608 shorts = 9216 B
#define W_LDS_OFF (WAVES * WAVE_LDS)   // 18432 shorts
#define SMEM_SHORTS (W_LDS_OFF + 2048) // 20480 shorts = 40960 B -> 4 blocks/CU
#define VB_STRIDE 68                   // padded fp32 row stride for reduction bufs
#define NITER 2                        // 2 iters x 4 waves x 32 rows = 256 rows
#define WS_STRIDE 2080                 // floats per partial: 2048 v + 32 suma

// COALESCED LOADS (round-9 change): rounds 0-8 all loaded with lane->addr
// stride 256 B (lane quad*16+l15 -> row l15, col quad*32B): 64 scattered
// 16-B requests per instruction, ~4x transaction amplification. All three
// structures plateaued at ~2.0-2.2 TB/s HBM read (vs 6.8 TB/s fills) and
// both post-load fixes (r7 cvt_pk, r8 gather->b64) were EXACT nulls -- the
// request pipe was the bound, not any compute chain. New mapping:
// lane -> row lane>>2, chunk lane&3: each instr = 16 contiguous 64-B
// segments. Fragments then redistributed through the nc LDS tile.

static __device__ __forceinline__ bf16x8 cvt8(float4 a, float4 b) {
    union { int i[4]; bf16x8 v; } u;
    asm("v_cvt_pk_bf16_f32 %0, %1, %2" : "=v"(u.i[0]) : "v"(a.x), "v"(a.y));
    asm("v_cvt_pk_bf16_f32 %0, %1, %2" : "=v"(u.i[1]) : "v"(a.z), "v"(a.w));
    asm("v_cvt_pk_bf16_f32 %0, %1, %2" : "=v"(u.i[2]) : "v"(b.x), "v"(b.y));
    asm("v_cvt_pk_bf16_f32 %0, %1, %2" : "=v"(u.i[3]) : "v"(b.z), "v"(b.w));
    return u.v;
}

// Sum across the 16 lanes of a DPP row (all lanes end with the total).
static __device__ __forceinline__ float row_sum16(float x) {
    union fi { float f; int i; };
    fi a, b; a.f = x;
    b.i = __builtin_amdgcn_mov_dpp(a.i, 0x128, 0xf, 0xf, false); a.f += b.f;
    b.i = __builtin_amdgcn_mov_dpp(a.i, 0x124, 0xf, 0xf, false); a.f += b.f;
    b.i = __builtin_amdgcn_mov_dpp(a.i, 0x122, 0xf, 0xf, false); a.f += b.f;
    b.i = __builtin_amdgcn_mov_dpp(a.i, 0x121, 0xf, 0xf, false); a.f += b.f;
    return a.f;
}

__global__ __launch_bounds__(256, 2)
void netvlad_partial(const float* __restrict__ R,
                     const float* __restrict__ W,
                     const float* __restrict__ bias,
                     float* __restrict__ ws)
{
    __shared__ short smem[SMEM_SHORTS];   // 40960 B

    const int tid  = threadIdx.x;
    const int wave = tid >> 6;
    const int lane = tid & 63;
    const int l15  = lane & 15;
    const int quad = lane >> 4;
    const int bid  = blockIdx.x;
    const int m    = bid >> 3;
    const int h    = bid & 7;

    short* nc_lds = smem + wave * WAVE_LDS;
    short* cn_lds = nc_lds + NC_SHORTS;
    short* a_lds  = cn_lds + CN_SHORTS;
    short* w_lds  = smem + W_LDS_OFF;

    const float* Rm = R + ((size_t)m * 2048 + (size_t)h * 256) * 64;

    // Stage W (32x64) as bf16 into shared LDS. Every wave writes identical
    // data -> benign race, no barrier needed (verified rounds 4-8).
#pragma unroll
    for (int kt = 0; kt < 2; ++kt)
#pragma unroll
        for (int cc = 0; cc < 2; ++cc) {
            const int k = kt*16 + l15;
            const int c = cc*32 + quad*8;
            const float* wp = W + k*64 + c;
            bf16x8 wv = cvt8(*(const float4*)wp, *(const float4*)(wp + 4));
            *(bf16x8*)(w_lds + k*64 + (c ^ ((k & 7) << 3))) = wv;
        }

    float bval[2];
    bval[0] = bias[l15];
    bval[1] = bias[16 + l15];

    f32x4 acc[2][4];   // v accumulator tiles [ktile][ctile], D-layout
#pragma unroll
    for (int kt = 0; kt < 2; ++kt)
#pragma unroll
        for (int ct = 0; ct < 4; ++ct)
            acc[kt][ct] = (f32x4){0.f, 0.f, 0.f, 0.f};
    float suma[2] = {0.f, 0.f};

    const int r16 = lane >> 2;        // row within 16-row s-tile (coalesced map)
    const int k4  = lane & 3;         // 16-B chunk within 64-B segment

#pragma unroll 1
    for (int it = 0; it < NITER; ++it) {
        const int n0 = it * (WAVES * 32) + wave * 32;

#pragma unroll
        for (int s = 0; s < 2; ++s) {
            // ---- coalesced load: 4 instrs, each 16 contiguous 64-B segs ----
            const float* lp = Rm + (size_t)(n0 + s*16 + r16)*64 + k4*4;
            const float4 x0 = *(const float4*)(lp);
            const float4 x1 = *(const float4*)(lp + 16);
            const float4 x2 = *(const float4*)(lp + 32);
            const float4 x3 = *(const float4*)(lp + 48);

            // cvt: cv.h[4j+e] = bf16 of col (k4*4 + 16j + e) of row r16
            union { int i[8]; short hh[16]; } cv;
            asm("v_cvt_pk_bf16_f32 %0, %1, %2" : "=v"(cv.i[0]) : "v"(x0.x), "v"(x0.y));
            asm("v_cvt_pk_bf16_f32 %0, %1, %2" : "=v"(cv.i[1]) : "v"(x0.z), "v"(x0.w));
            asm("v_cvt_pk_bf16_f32 %0, %1, %2" : "=v"(cv.i[2]) : "v"(x1.x), "v"(x1.y));
            asm("v_cvt_pk_bf16_f32 %0, %1, %2" : "=v"(cv.i[3]) : "v"(x1.z), "v"(x1.w));
            asm("v_cvt_pk_bf16_f32 %0, %1, %2" : "=v"(cv.i[4]) : "v"(x2.x), "v"(x2.y));
            asm("v_cvt_pk_bf16_f32 %0, %1, %2" : "=v"(cv.i[5]) : "v"(x2.z), "v"(x2.w));
            asm("v_cvt_pk_bf16_f32 %0, %1, %2" : "=v"(cv.i[6]) : "v"(x3.x), "v"(x3.y));
            asm("v_cvt_pk_bf16_f32 %0, %1, %2" : "=v"(cv.i[7]) : "v"(x3.z), "v"(x3.w));

            // ---- nc tile: 4 x ds_write_b64, XOR-swizzled ----
            {
                short* ncw = nc_lds + r16*64;
                const int swr = (r16 & 7) << 3;
                *(bf16x4*)(ncw + ((k4*4 +  0) ^ swr)) = *(bf16x4*)&cv.hh[0];
                *(bf16x4*)(ncw + ((k4*4 + 16) ^ swr)) = *(bf16x4*)&cv.hh[4];
                *(bf16x4*)(ncw + ((k4*4 + 32) ^ swr)) = *(bf16x4*)&cv.hh[8];
                *(bf16x4*)(ncw + ((k4*4 + 48) ^ swr)) = *(bf16x4*)&cv.hh[12];
            }
            // ---- cn tile: 16 x ds_write_b16 transpose scatter ----
            {
                const int n = s*16 + r16;
#pragma unroll
                for (int j = 0; j < 4; ++j)
#pragma unroll
                    for (int e = 0; e < 4; ++e)
                        cn_lds[(k4*4 + 16*j + e)*CN_STRIDE + n] = cv.hh[4*j + e];
            }

            // fence: cross-lane LDS write->read (per-thread alias analysis
            // cannot see the dependency; DS pipe is in-order per wave)
            __builtin_amdgcn_sched_barrier(0);

            // ---- af fragments from nc (2 x ds_read_b128) ----
            const int swl = (l15 & 7) << 3;
            const bf16x8 af0 = *(const bf16x8*)(nc_lds + l15*64 + ((quad*8)      ^ swl));
            const bf16x8 af1 = *(const bf16x8*)(nc_lds + l15*64 + ((32 + quad*8) ^ swl));

            // GEMM1 for this s: W fragments re-read from LDS per kt
            f32x4 d1s[2];
#pragma unroll
            for (int kt = 0; kt < 2; ++kt) {
                const int k = kt*16 + l15;
                const bf16x8 w0 = *(const bf16x8*)(w_lds + k*64 + ((quad*8)      ^ ((k & 7) << 3)));
                const bf16x8 w1 = *(const bf16x8*)(w_lds + k*64 + ((32 + quad*8) ^ ((k & 7) << 3)));
                f32x4 d = (f32x4){0.f, 0.f, 0.f, 0.f};
                d = __builtin_amdgcn_mfma_f32_16x16x32_bf16(af0, w0, d, 0, 0, 0);
                d = __builtin_amdgcn_mfma_f32_16x16x32_bf16(af1, w1, d, 0, 0, 0);
                d1s[kt] = d;
            }

            // softmax over k (row = s*16 + quad*4 + r, k = kt*16 + l15)
            float a0v[4], a1v[4];
            float a0s = 0.f, a1s = 0.f;
#pragma unroll
            for (int r = 0; r < 4; ++r) {
                float l0 = d1s[0][r] + bval[0];
                float l1 = d1s[1][r] + bval[1];
                float e0 = __expf(l0);
                float e1 = __expf(l1);
                float ss = row_sum16(e0 + e1);             // VALU DPP
                float rs = __builtin_amdgcn_rcpf(ss);
                a0v[r] = e0 * rs; a1v[r] = e1 * rs;
                a0s += a0v[r]; a1s += a1v[r];
            }
            suma[0] += a0s; suma[1] += a1s;
            union { int i[2]; bf16x4 v; } p0, p1;
            asm("v_cvt_pk_bf16_f32 %0, %1, %2" : "=v"(p0.i[0]) : "v"(a0v[0]), "v"(a0v[1]));
            asm("v_cvt_pk_bf16_f32 %0, %1, %2" : "=v"(p0.i[1]) : "v"(a0v[2]), "v"(a0v[3]));
            asm("v_cvt_pk_bf16_f32 %0, %1, %2" : "=v"(p1.i[0]) : "v"(a1v[0]), "v"(a1v[1]));
            asm("v_cvt_pk_bf16_f32 %0, %1, %2" : "=v"(p1.i[1]) : "v"(a1v[2]), "v"(a1v[3]));
            *(bf16x4*)(a_lds + l15*A_STRIDE        + s*16 + quad*4) = p0.v;
            *(bf16x4*)(a_lds + (16 + l15)*A_STRIDE + s*16 + quad*4) = p1.v;
        }

        // fence before GEMM2's cross-lane reads of a_lds / cn_lds
        __builtin_amdgcn_sched_barrier(0);

        // A2 fragments: A[m=k][kdim=n] -> contiguous 16 B from a_lds
        bf16x8 a2[2];
#pragma unroll
        for (int kt = 0; kt < 2; ++kt)
            a2[kt] = *(bf16x8*)(a_lds + (kt*16 + l15)*A_STRIDE + quad*8);

        // GEMM2: v += a^T r. B-frag j = r[n=quad*8+j][c=ct*16+l15]
        // = cn[c][quad*8+j]: two contiguous ds_read_b64 per ct (8B-aligned).
#pragma unroll
        for (int ct = 0; ct < 4; ++ct) {
            const short* bp = cn_lds + (ct*16 + l15)*CN_STRIDE + quad*8;
            union { bf16x4 h2[2]; bf16x8 v; } b2;
            b2.h2[0] = *(const bf16x4*)bp;
            b2.h2[1] = *(const bf16x4*)(bp + 4);
#pragma unroll
            for (int kt = 0; kt < 2; ++kt)
                acc[kt][ct] = __builtin_amdgcn_mfma_f32_16x16x32_bf16(a2[kt], b2.v, acc[kt][ct], 0, 0, 0);
        }

        // fence before next iteration overwrites nc/cn/a
        __builtin_amdgcn_sched_barrier(0);
    }

    // suma held per-lane for k = l15 (+16): fold the 4 quads together
#pragma unroll
    for (int kt = 0; kt < 2; ++kt) {
        suma[kt] += __shfl_xor(suma[kt], 16);
        suma[kt] += __shfl_xor(suma[kt], 32);
    }

    // cross-wave log-tree reduction. vbuf aliases the (dead) staging LDS;
    // suma_buf aliases the (dead) W region.
    float* vbuf = (float*)smem;
    float* suma_buf = (float*)(smem + W_LDS_OFF);
    __syncthreads();
#pragma unroll
    for (int step = 2; step >= 1; step >>= 1) {
        if (wave >= step && wave < 2*step) {
            float* dst = vbuf + (wave - step) * (32 * VB_STRIDE);
#pragma unroll
            for (int kt = 0; kt < 2; ++kt)
#pragma unroll
                for (int ct = 0; ct < 4; ++ct)
#pragma unroll
                    for (int r = 0; r < 4; ++r)
                        dst[(kt*16 + quad*4 + r)*VB_STRIDE + ct*16 + l15] = acc[kt][ct][r];
            if (lane < 16) {
                suma_buf[(wave - step)*32 + lane]      = suma[0];
                suma_buf[(wave - step)*32 + lane + 16] = suma[1];
            }
        }
        __syncthreads();
        if (wave < step) {
            const float* src = vbuf + wave * (32 * VB_STRIDE);
#pragma unroll
            for (int kt = 0; kt < 2; ++kt)
#pragma unroll
                for (int ct = 0; ct < 4; ++ct)
#pragma unroll
                    for (int r = 0; r < 4; ++r)
                        acc[kt][ct][r] += src[(kt*16 + quad*4 + r)*VB_STRIDE + ct*16 + l15];
            suma[0] += suma_buf[wave*32 + l15];
            suma[1] += suma_buf[wave*32 + l15 + 16];
        }
        __syncthreads();
    }

    // wave 0: write block partial {v (32x64), suma (32)} to workspace
    if (wave == 0) {
        float* wp = ws + (size_t)bid * WS_STRIDE;
#pragma unroll
        for (int kt = 0; kt < 2; ++kt)
#pragma unroll
            for (int r = 0; r < 4; ++r) {
                const int k = kt*16 + quad*4 + r;
#pragma unroll
                for (int ct = 0; ct < 4; ++ct)
                    wp[k*64 + ct*16 + l15] = acc[kt][ct][r];
            }
        if (lane < 16) {
            wp[2048 + lane]      = suma[0];
            wp[2048 + 16 + lane] = suma[1];
        }
    }
}

// Kernel 2: combine the eight N-slices and apply  v - suma[k]*cent[k][c].
__global__ __launch_bounds__(512)
void netvlad_combine(const float* __restrict__ ws,
                     const float* __restrict__ cent,
                     float* __restrict__ out)
{
    const int m   = blockIdx.x;
    const int tid = threadIdx.x;
    const float* pb = ws + (size_t)(8*m) * WS_STRIDE;

    const int k  = tid >> 4;          // 0..31
    const int c0 = (tid & 15) << 2;   // 0,4,...,60
    const int off = k*64 + c0;

    float s = 0.f;
    float4 v = {0.f, 0.f, 0.f, 0.f};
#pragma unroll
    for (int i = 0; i < 8; ++i) {
        const float* p = pb + (size_t)i * WS_STRIDE;
        s += p[2048 + k];
        const float4 vi = *(const float4*)(p + off);
        v.x += vi.x; v.y += vi.y; v.z += vi.z; v.w += vi.w;
    }

    const float4 cv = *(const float4*)(cent + off);
    float4 o;
    o.x = v.x - s * cv.x;
    o.y = v.y - s * cv.y;
    o.z = v.z - s * cv.z;
    o.w = v.w - s * cv.w;
    *(float4*)(out + (size_t)m * 2048 + off) = o;
}

extern "C" void kernel_launch(void* const* d_in, const int* in_sizes, int n_in,
                              void* d_out, int out_size, void* d_ws, size_t ws_size,
                              hipStream_t stream) {
    (void)in_sizes; (void)n_in; (void)out_size; (void)ws_size;
    const float* R = (const float*)d_in[0];   // R_seq (8,32,2048,64) fp32
    const float* W = (const float*)d_in[1];   // W (32,64) fp32
    const float* b = (const float*)d_in[2];   // b (32,) fp32
    const float* c = (const float*)d_in[3];   // centroids (32,64) fp32
    float* out = (float*)d_out;               // (8,32,32,64) fp32
    float* ws  = (float*)d_ws;                // 2048 * 2080 floats = 17 MB partials

    hipLaunchKernelGGL(netvlad_partial, dim3(2048), dim3(256), 0, stream, R, W, b, ws);
    hipLaunchKernelGGL(netvlad_combine, dim3(256), dim3(512), 0, stream, ws, c, out);
}